// Round 1
// baseline (497.177 us; speedup 1.0000x reference)
//
#include <hip/hip_runtime.h>
#include <hip/hip_bf16.h>
#include <math.h>

// ---------------- problem constants (from setup_inputs, fixed) ----------------
constexpr int BATCH    = 4;
constexpr int D_MODEL  = 256;
constexpr int N_HEADS  = 8;
constexpr int N_LEVELS = 4;
constexpr int N_POINTS = 4;
constexpr int HEAD_DIM = 32;
constexpr int LEN_IN   = 5440;   // 64*64 + 32*32 + 16*16 + 8*8
constexpr int LEN_Q    = 5440;

__device__ __constant__ int c_lvl_h[4]     = {64, 32, 16, 8};
__device__ __constant__ int c_lvl_w[4]     = {64, 32, 16, 8};
__device__ __constant__ int c_lvl_start[4] = {0, 4096, 5120, 5376};

// ---------------- fp32 tiled GEMM with fused bias ----------------
// C[M,N] = A[M,K] @ W[K,N] + bias[N]
// BM=BN=64, BK=16, 256 threads, 4x4 acc per thread.
// M % 64 == 0, N % 64 == 0, K % 16 == 0 hold for all four calls.
__global__ __launch_bounds__(256) void gemm_bias_f32(
    const float* __restrict__ A, const float* __restrict__ W,
    const float* __restrict__ bias, float* __restrict__ C,
    int M, int N, int K)
{
    constexpr int BM = 64, BN = 64, BK = 16;
    __shared__ float As[BK][BM];   // A tile, transposed (k-major)
    __shared__ float Bs[BK][BN];

    const int tid = threadIdx.x;
    const int bm = blockIdx.y * BM;
    const int bn = blockIdx.x * BN;
    const int tx = tid & 15;       // 0..15 -> col group (4 cols)
    const int ty = tid >> 4;       // 0..15 -> row group (4 rows)

    // staging indices
    const int arow = tid >> 2;           // 0..63
    const int acol = (tid & 3) * 4;      // 0,4,8,12
    const int brow = tid >> 4;           // 0..15
    const int bcol = (tid & 15) * 4;     // 0..60

    float acc[4][4] = {};

    for (int k0 = 0; k0 < K; k0 += BK) {
        float4 av = *(const float4*)(A + (size_t)(bm + arow) * K + k0 + acol);
        float4 bv = *(const float4*)(W + (size_t)(k0 + brow) * N + bn + bcol);
        __syncthreads();   // previous iteration's readers done before overwrite
        As[acol + 0][arow] = av.x;
        As[acol + 1][arow] = av.y;
        As[acol + 2][arow] = av.z;
        As[acol + 3][arow] = av.w;
        *(float4*)(&Bs[brow][bcol]) = bv;
        __syncthreads();
#pragma unroll
        for (int kk = 0; kk < BK; kk++) {
            float4 a4 = *(const float4*)(&As[kk][ty * 4]);
            float4 b4 = *(const float4*)(&Bs[kk][tx * 4]);
            float ar[4] = {a4.x, a4.y, a4.z, a4.w};
            float br[4] = {b4.x, b4.y, b4.z, b4.w};
#pragma unroll
            for (int i = 0; i < 4; i++)
#pragma unroll
                for (int j = 0; j < 4; j++)
                    acc[i][j] = fmaf(ar[i], br[j], acc[i][j]);
        }
    }

    float4 bb = *(const float4*)(bias + bn + tx * 4);
    float br[4] = {bb.x, bb.y, bb.z, bb.w};
#pragma unroll
    for (int i = 0; i < 4; i++) {
        int row = bm + ty * 4 + i;
        float4 o;
        o.x = acc[i][0] + br[0];
        o.y = acc[i][1] + br[1];
        o.z = acc[i][2] + br[2];
        o.w = acc[i][3] + br[3];
        *(float4*)(C + (size_t)row * N + bn + tx * 4) = o;
    }
}

// ---------------- fused softmax + deformable bilinear sampling ----------------
// One block per (b, q). 256 threads = 8 heads x 32 channels.
// value: [B, LEN_IN, 8, 32]   (output of value projection)
// refp : [B, LQ, 4, 2]
// off  : [B, LQ, 256]  (= [.., 8, 4, 4, 2])
// attn : [B, LQ, 128]  (= [.., 8, 16] logits, softmax over the 16)
// mid  : [B, LQ, 256]  (pre-W_out features, channel = head*32 + c)
__global__ __launch_bounds__(256) void msda_sample(
    const float* __restrict__ value, const float* __restrict__ refp,
    const float* __restrict__ off, const float* __restrict__ attn,
    float* __restrict__ mid)
{
    const int bq = blockIdx.x;          // b*LQ + q
    const int b  = bq / LEN_Q;
    const int tid  = threadIdx.x;
    const int head = tid >> 5;
    const int c    = tid & 31;

    __shared__ float wts[N_HEADS][16];

    // ---- softmax over the 16 (level,point) logits of each head ----
    const float* ap = attn + (size_t)bq * (N_HEADS * 16) + head * 16;
    if (c < 16) wts[head][c] = ap[c];
    __syncthreads();
    float inv_s = 0.f;
    if (c < 16) {
        float m = -INFINITY;
#pragma unroll
        for (int j = 0; j < 16; j++) m = fmaxf(m, wts[head][j]);
        float e = expf(wts[head][c] - m);
        __syncthreads();
        wts[head][c] = e;
    } else {
        __syncthreads();
    }
    __syncthreads();
    if (c < 16) {
        float s = 0.f;
#pragma unroll
        for (int j = 0; j < 16; j++) s += wts[head][j];
        inv_s = 1.f / s;
    }
    __syncthreads();
    if (c < 16) wts[head][c] *= inv_s;
    __syncthreads();

    // ---- sampling ----
    const float* off_p = off + (size_t)bq * (N_HEADS * 32) + head * 32;
    const float* ref_p = refp + (size_t)bq * (N_LEVELS * 2);
    const float* vbase = value + ((size_t)b * LEN_IN) * D_MODEL + head * HEAD_DIM + c;

    float acc = 0.f;
#pragma unroll
    for (int l = 0; l < N_LEVELS; l++) {
        const int H = c_lvl_h[l], W = c_lvl_w[l], st = c_lvl_start[l];
        const float fW = (float)W, fH = (float)H;
        const float rx = ref_p[l * 2 + 0];
        const float ry = ref_p[l * 2 + 1];
#pragma unroll
        for (int p = 0; p < N_POINTS; p++) {
            const float ox = off_p[l * 8 + p * 2 + 0];
            const float oy = off_p[l * 8 + p * 2 + 1];
            const float aw = wts[head][l * 4 + p];
            // loc = ref + off/norm;  x = loc*W - 0.5 (grid_sample align_corners=False)
            const float x = (rx + ox / fW) * fW - 0.5f;
            const float y = (ry + oy / fH) * fH - 0.5f;
            const float x0f = floorf(x), y0f = floorf(y);
            const float wx = x - x0f, wy = y - y0f;
            const int x0 = (int)x0f, y0 = (int)y0f;
            const int x1 = x0 + 1,  y1 = y0 + 1;
            const bool vx0 = (x0 >= 0) & (x0 < W);
            const bool vx1 = (x1 >= 0) & (x1 < W);
            const bool vy0 = (y0 >= 0) & (y0 < H);
            const bool vy1 = (y1 >= 0) & (y1 < H);
            float s = 0.f;
            if (vy0) {
                const size_t rb = (size_t)(st + y0 * W) * D_MODEL;
                if (vx0) s += (1.f - wx) * (1.f - wy) * vbase[rb + (size_t)x0 * D_MODEL];
                if (vx1) s += wx * (1.f - wy) * vbase[rb + (size_t)x1 * D_MODEL];
            }
            if (vy1) {
                const size_t rb = (size_t)(st + y1 * W) * D_MODEL;
                if (vx0) s += (1.f - wx) * wy * vbase[rb + (size_t)x0 * D_MODEL];
                if (vx1) s += wx * wy * vbase[rb + (size_t)x1 * D_MODEL];
            }
            acc = fmaf(aw, s, acc);
        }
    }
    mid[(size_t)bq * D_MODEL + tid] = acc;
}

// ---------------- launch ----------------
extern "C" void kernel_launch(void* const* d_in, const int* in_sizes, int n_in,
                              void* d_out, int out_size, void* d_ws, size_t ws_size,
                              hipStream_t stream)
{
    const float* query  = (const float*)d_in[0];   // [B, LQ, 256]
    const float* refp   = (const float*)d_in[1];   // [B, LQ, 4, 2]
    const float* inflat = (const float*)d_in[2];   // [B, LEN_IN, 256]
    // d_in[3], d_in[4]: spatial shapes / level starts (int64) — compile-time constants
    const float* W_val  = (const float*)d_in[5];
    const float* b_val  = (const float*)d_in[6];
    const float* W_off  = (const float*)d_in[7];
    const float* b_off  = (const float*)d_in[8];
    const float* W_attn = (const float*)d_in[9];
    const float* b_attn = (const float*)d_in[10];
    const float* W_out  = (const float*)d_in[11];
    const float* b_out  = (const float*)d_in[12];
    float* out = (float*)d_out;

    const int M = BATCH * LEN_Q;                       // 21760
    float* ws    = (float*)d_ws;
    float* value = ws;                                  // [B, LEN_IN, 256]
    float* off   = value + (size_t)M * D_MODEL;         // [B, LQ, 256]
    float* attn  = off   + (size_t)M * D_MODEL;         // [B, LQ, 128]
    float* mid   = attn  + (size_t)M * 128;             // [B, LQ, 256]

    dim3 blk(256);
    // value projection: [M,256] @ [256,256]
    gemm_bias_f32<<<dim3(D_MODEL / 64, M / 64), blk, 0, stream>>>(
        inflat, W_val, b_val, value, M, D_MODEL, D_MODEL);
    // offsets: [M,256] @ [256,256]
    gemm_bias_f32<<<dim3(D_MODEL / 64, M / 64), blk, 0, stream>>>(
        query, W_off, b_off, off, M, D_MODEL, D_MODEL);
    // attention logits: [M,256] @ [256,128]
    gemm_bias_f32<<<dim3(128 / 64, M / 64), blk, 0, stream>>>(
        query, W_attn, b_attn, attn, M, 128, D_MODEL);
    // softmax + deformable sampling
    msda_sample<<<dim3(M), blk, 0, stream>>>(value, refp, off, attn, mid);
    // output projection: [M,256] @ [256,256]
    gemm_bias_f32<<<dim3(D_MODEL / 64, M / 64), blk, 0, stream>>>(
        mid, W_out, b_out, out, M, D_MODEL, D_MODEL);
}

// Round 2
// 323.872 us; speedup vs baseline: 1.5351x; 1.5351x over previous
//
#include <hip/hip_runtime.h>
#include <hip/hip_bf16.h>
#include <math.h>

// ---------------- problem constants (from setup_inputs, fixed) ----------------
constexpr int BATCH    = 4;
constexpr int D_MODEL  = 256;
constexpr int N_HEADS  = 8;
constexpr int N_LEVELS = 4;
constexpr int N_POINTS = 4;
constexpr int HEAD_DIM = 32;
constexpr int LEN_IN   = 5440;   // 64*64 + 32*32 + 16*16 + 8*8
constexpr int LEN_Q    = 5440;

// ---------------- fp32 tiled GEMM with fused bias ----------------
// C[M,N] = A[M,K] @ W[K,N] + bias[N]
// BM=128, BN=64, BK=16, 256 threads, 8x4 acc per thread.
__global__ __launch_bounds__(256) void gemm_bias_f32(
    const float* __restrict__ A, const float* __restrict__ W,
    const float* __restrict__ bias, float* __restrict__ C,
    int M, int N, int K)
{
    constexpr int BM = 128, BN = 64, BK = 16;
    __shared__ float As[BK][BM];   // A tile, k-major (transposed)
    __shared__ float Bs[BK][BN];

    const int tid = threadIdx.x;
    const int bm = blockIdx.y * BM;
    const int bn = blockIdx.x * BN;
    const int tx = tid & 15;        // B col group (4 cols)
    const int ty = tid >> 4;        // A row group (8 rows)

    const int arow = tid >> 1;            // 0..127
    const int acol = (tid & 1) * 8;       // 0 or 8
    const int brow = tid >> 4;            // 0..15
    const int bcol = (tid & 15) * 4;      // 0..60

    float acc[8][4] = {};

    for (int k0 = 0; k0 < K; k0 += BK) {
        const float* ap = A + (size_t)(bm + arow) * K + k0 + acol;
        float4 av0 = *(const float4*)(ap);
        float4 av1 = *(const float4*)(ap + 4);
        float4 bv  = *(const float4*)(W + (size_t)(k0 + brow) * N + bn + bcol);
        __syncthreads();
        As[acol + 0][arow] = av0.x;
        As[acol + 1][arow] = av0.y;
        As[acol + 2][arow] = av0.z;
        As[acol + 3][arow] = av0.w;
        As[acol + 4][arow] = av1.x;
        As[acol + 5][arow] = av1.y;
        As[acol + 6][arow] = av1.z;
        As[acol + 7][arow] = av1.w;
        *(float4*)(&Bs[brow][bcol]) = bv;
        __syncthreads();
#pragma unroll
        for (int kk = 0; kk < BK; kk++) {
            float4 a0 = *(const float4*)(&As[kk][ty * 8]);
            float4 a1 = *(const float4*)(&As[kk][ty * 8 + 4]);
            float4 b4 = *(const float4*)(&Bs[kk][tx * 4]);
            float ar[8] = {a0.x, a0.y, a0.z, a0.w, a1.x, a1.y, a1.z, a1.w};
            float br[4] = {b4.x, b4.y, b4.z, b4.w};
#pragma unroll
            for (int i = 0; i < 8; i++)
#pragma unroll
                for (int j = 0; j < 4; j++)
                    acc[i][j] = fmaf(ar[i], br[j], acc[i][j]);
        }
    }

    float4 bb = *(const float4*)(bias + bn + tx * 4);
#pragma unroll
    for (int i = 0; i < 8; i++) {
        int row = bm + ty * 8 + i;
        float4 o;
        o.x = acc[i][0] + bb.x;
        o.y = acc[i][1] + bb.y;
        o.z = acc[i][2] + bb.z;
        o.w = acc[i][3] + bb.w;
        *(float4*)(C + (size_t)row * N + bn + tx * 4) = o;
    }
}

// ---------------- fused softmax + deformable bilinear sampling ----------------
// Block = 256 threads = 4 queries x (8 heads x 8 lanes); each lane owns 4
// channels (float4). Softmax computed redundantly per lane in registers (no
// LDS, no barriers); normalization folded into final scale by 1/sum(e).
__global__ __launch_bounds__(256) void msda_sample(
    const float* __restrict__ value, const float* __restrict__ refp,
    const float* __restrict__ off, const float* __restrict__ attn,
    float* __restrict__ mid)
{
    constexpr int LVL_H[4]  = {64, 32, 16, 8};
    constexpr int LVL_W[4]  = {64, 32, 16, 8};
    constexpr int LVL_ST[4] = {0, 4096, 5120, 5376};

    const int tid  = threadIdx.x;
    const int bq   = blockIdx.x * 4 + (tid >> 6);
    const int b    = bq / LEN_Q;
    const int t64  = tid & 63;
    const int head = t64 >> 3;
    const int c4   = (t64 & 7) * 4;

    // ---- load 16 attn logits (this head) ----
    const float* ap = attn + (size_t)bq * (N_HEADS * 16) + head * 16;
    float4 l0 = ((const float4*)ap)[0];
    float4 l1 = ((const float4*)ap)[1];
    float4 l2 = ((const float4*)ap)[2];
    float4 l3 = ((const float4*)ap)[3];
    float lg[16] = {l0.x, l0.y, l0.z, l0.w, l1.x, l1.y, l1.z, l1.w,
                    l2.x, l2.y, l2.z, l2.w, l3.x, l3.y, l3.z, l3.w};
    float mx = lg[0];
#pragma unroll
    for (int j = 1; j < 16; j++) mx = fmaxf(mx, lg[j]);

    // ---- load 32 offsets (this head) and 8 reference coords ----
    const float* op = off + (size_t)bq * (N_HEADS * 32) + head * 32;
    float4 ov[8];
#pragma unroll
    for (int j = 0; j < 8; j++) ov[j] = ((const float4*)op)[j];
    const float* rp = refp + (size_t)bq * (N_LEVELS * 2);
    float4 r0 = ((const float4*)rp)[0];   // (rx0, ry0, rx1, ry1)
    float4 r1 = ((const float4*)rp)[1];   // (rx2, ry2, rx3, ry3)
    float rx[4] = {r0.x, r0.z, r1.x, r1.z};
    float ry[4] = {r0.y, r0.w, r1.y, r1.w};

    const float* vbase = value + ((size_t)b * LEN_IN) * D_MODEL + head * HEAD_DIM + c4;

    float4 acc = {0.f, 0.f, 0.f, 0.f};
    float esum = 0.f;

#pragma unroll
    for (int l = 0; l < N_LEVELS; l++) {
        const int H = LVL_H[l], W = LVL_W[l], st = LVL_ST[l];
        const float fW = (float)W, fH = (float)H;
#pragma unroll
        for (int p = 0; p < N_POINTS; p++) {
            const float* o2 = &ov[l * 2].x;           // 8 floats per level
            const float ox = o2[p * 2 + 0];
            const float oy = o2[p * 2 + 1];
            // x = (rx + ox/W)*W - 0.5   (W,H are powers of two -> /,* exact)
            const float x = (rx[l] + ox / fW) * fW - 0.5f;
            const float y = (ry[l] + oy / fH) * fH - 0.5f;
            const float x0f = floorf(x), y0f = floorf(y);
            const float wx = x - x0f, wy = y - y0f;
            const int ix0 = (int)x0f, iy0 = (int)y0f;
            const int ix1 = ix0 + 1,  iy1 = iy0 + 1;
            const float vx0 = (ix0 >= 0 && ix0 < W) ? 1.f : 0.f;
            const float vx1 = (ix1 >= 0 && ix1 < W) ? 1.f : 0.f;
            const float vy0 = (iy0 >= 0 && iy0 < H) ? 1.f : 0.f;
            const float vy1 = (iy1 >= 0 && iy1 < H) ? 1.f : 0.f;
            const int cx0 = min(max(ix0, 0), W - 1);
            const int cx1 = min(max(ix1, 0), W - 1);
            const int cy0 = min(max(iy0, 0), H - 1);
            const int cy1 = min(max(iy1, 0), H - 1);
            const float hx0 = (1.f - wx) * vx0, hx1 = wx * vx1;
            const float hy0 = (1.f - wy) * vy0, hy1 = wy * vy1;

            const float* row0 = vbase + (size_t)(st + cy0 * W) * D_MODEL;
            const float* row1 = vbase + (size_t)(st + cy1 * W) * D_MODEL;
            float4 c00 = *(const float4*)(row0 + (size_t)cx0 * D_MODEL);
            float4 c01 = *(const float4*)(row0 + (size_t)cx1 * D_MODEL);
            float4 c10 = *(const float4*)(row1 + (size_t)cx0 * D_MODEL);
            float4 c11 = *(const float4*)(row1 + (size_t)cx1 * D_MODEL);

            const float w00 = hx0 * hy0, w01 = hx1 * hy0;
            const float w10 = hx0 * hy1, w11 = hx1 * hy1;

            float4 t;
            t.x = w00 * c00.x + w01 * c01.x + w10 * c10.x + w11 * c11.x;
            t.y = w00 * c00.y + w01 * c01.y + w10 * c10.y + w11 * c11.y;
            t.z = w00 * c00.z + w01 * c01.z + w10 * c10.z + w11 * c11.z;
            t.w = w00 * c00.w + w01 * c01.w + w10 * c10.w + w11 * c11.w;

            const float e = __expf(lg[l * 4 + p] - mx);
            esum += e;
            acc.x = fmaf(e, t.x, acc.x);
            acc.y = fmaf(e, t.y, acc.y);
            acc.z = fmaf(e, t.z, acc.z);
            acc.w = fmaf(e, t.w, acc.w);
        }
    }

    const float inv_s = 1.f / esum;
    acc.x *= inv_s; acc.y *= inv_s; acc.z *= inv_s; acc.w *= inv_s;
    *(float4*)(mid + (size_t)bq * D_MODEL + head * HEAD_DIM + c4) = acc;
}

// ---------------- launch ----------------
extern "C" void kernel_launch(void* const* d_in, const int* in_sizes, int n_in,
                              void* d_out, int out_size, void* d_ws, size_t ws_size,
                              hipStream_t stream)
{
    const float* query  = (const float*)d_in[0];   // [B, LQ, 256]
    const float* refp   = (const float*)d_in[1];   // [B, LQ, 4, 2]
    const float* inflat = (const float*)d_in[2];   // [B, LEN_IN, 256]
    const float* W_val  = (const float*)d_in[5];
    const float* b_val  = (const float*)d_in[6];
    const float* W_off  = (const float*)d_in[7];
    const float* b_off  = (const float*)d_in[8];
    const float* W_attn = (const float*)d_in[9];
    const float* b_attn = (const float*)d_in[10];
    const float* W_out  = (const float*)d_in[11];
    const float* b_out  = (const float*)d_in[12];
    float* out = (float*)d_out;

    const int M = BATCH * LEN_Q;                       // 21760
    float* ws    = (float*)d_ws;
    float* value = ws;                                  // [B, LEN_IN, 256]
    float* off   = value + (size_t)M * D_MODEL;         // [B, LQ, 256]
    float* attn  = off   + (size_t)M * D_MODEL;         // [B, LQ, 128]
    float* mid   = attn  + (size_t)M * 128;             // [B, LQ, 256]

    dim3 blk(256);
    gemm_bias_f32<<<dim3(D_MODEL / 64, M / 128), blk, 0, stream>>>(
        inflat, W_val, b_val, value, M, D_MODEL, D_MODEL);
    gemm_bias_f32<<<dim3(D_MODEL / 64, M / 128), blk, 0, stream>>>(
        query, W_off, b_off, off, M, D_MODEL, D_MODEL);
    gemm_bias_f32<<<dim3(128 / 64, M / 128), blk, 0, stream>>>(
        query, W_attn, b_attn, attn, M, 128, D_MODEL);
    msda_sample<<<dim3(M / 4), blk, 0, stream>>>(value, refp, off, attn, mid);
    gemm_bias_f32<<<dim3(D_MODEL / 64, M / 128), blk, 0, stream>>>(
        mid, W_out, b_out, out, M, D_MODEL, D_MODEL);
}

// Round 3
// 206.105 us; speedup vs baseline: 2.4123x; 1.5714x over previous
//
#include <hip/hip_runtime.h>
#include <hip/hip_bf16.h>
#include <math.h>

typedef unsigned short ushort_t;
typedef __attribute__((ext_vector_type(8))) short bf16x8;
typedef __attribute__((ext_vector_type(4))) float f32x4;

constexpr int BATCH   = 4;
constexpr int D_MODEL = 256;
constexpr int LEN_IN  = 5440;
constexpr int LEN_Q   = 5440;
constexpr int M_TOT   = BATCH * LEN_Q;   // 21760

#define ASG __attribute__((address_space(1)))
#define ASL __attribute__((address_space(3)))

__device__ __forceinline__ void gld16(const void* g, void* l) {
    __builtin_amdgcn_global_load_lds((ASG const void*)g, (ASL void*)l, 16, 0, 0);
}

__device__ __forceinline__ ushort_t bfbits(float x) {
    __hip_bfloat16 h = __float2bfloat16(x);
    ushort_t u; __builtin_memcpy(&u, &h, 2); return u;
}
__device__ __forceinline__ unsigned pk2(float a, float b) {
    return (unsigned)bfbits(a) | ((unsigned)bfbits(b) << 16);
}

// ======================= pack / convert / transpose =======================
// blocks [0,2720)    : in_flat f32 -> in_bf   (2048 elems/block)
// blocks [2720,5440) : query   f32 -> q_bf
// blocks [5440,5472) : W_val  [256,256] -> wvT  [256n][256k] bf16
// blocks [5472,5504) : W_out  [256,256] -> woutT[256n][256k] bf16
// blocks [5504,5552) : W_off|W_attn -> woaT [384n][256k] bf16
// block  5552        : bias concat (b_off | b_attn) -> f32[384]
__global__ __launch_bounds__(256) void pack_inputs(
    const float* __restrict__ inflat, const float* __restrict__ query,
    const float* __restrict__ Wv, const float* __restrict__ Wo,
    const float* __restrict__ Wa, const float* __restrict__ Wout,
    const float* __restrict__ b_off, const float* __restrict__ b_attn,
    ushort_t* __restrict__ in_bf, ushort_t* __restrict__ q_bf,
    ushort_t* __restrict__ wvT, ushort_t* __restrict__ woaT,
    ushort_t* __restrict__ woutT, float* __restrict__ bias_oa)
{
    const int blk = blockIdx.x, tid = threadIdx.x;
    if (blk < 5440) {
        const float* src = (blk < 2720) ? inflat : query;
        ushort_t*    dst = (blk < 2720) ? in_bf : q_bf;
        const int rb = (blk < 2720) ? blk : blk - 2720;
        const size_t base = (size_t)rb * 2048 + tid * 8;
        float4 a = *(const float4*)(src + base);
        float4 b = *(const float4*)(src + base + 4);
        uint4 o;
        o.x = pk2(a.x, a.y); o.y = pk2(a.z, a.w);
        o.z = pk2(b.x, b.y); o.w = pk2(b.z, b.w);
        *(uint4*)(dst + base) = o;
    } else if (blk < 5504) {
        const float* src = (blk < 5472) ? Wv : Wout;
        ushort_t*    dst = (blk < 5472) ? wvT : woutT;
        const int base = (blk - ((blk < 5472) ? 5440 : 5472)) * 2048;
#pragma unroll
        for (int i = 0; i < 8; i++) {
            const int idx = base + i * 256 + tid;
            const int k = idx >> 8, n = idx & 255;
            dst[n * 256 + k] = bfbits(src[idx]);
        }
    } else if (blk < 5552) {
        const int base = (blk - 5504) * 2048;
#pragma unroll
        for (int i = 0; i < 8; i++) {
            const int idx = base + i * 256 + tid;   // < 98304
            const int k = idx / 384, j = idx - k * 384;
            const float v = (j < 256) ? Wo[k * 256 + j] : Wa[k * 128 + (j - 256)];
            woaT[j * 256 + k] = bfbits(v);
        }
    } else {
        bias_oa[tid] = b_off[tid];
        if (tid < 128) bias_oa[256 + tid] = b_attn[tid];
    }
}

// ======================= bf16 MFMA GEMM core =======================
// C[M,N] = A[M,256] @ BT[N,256]^T + bias[N]
// 128x128 tile, BK=32, 256 threads (4 waves), wave = 64x64 quadrant of
// 4x4 mfma_f32_16x16x32_bf16. Staging via global_load_lds dwordx4.
template <bool OUT_BF16>
__device__ __forceinline__ void gemm_core(
    const ushort_t* __restrict__ A, const ushort_t* __restrict__ BT,
    const float* __restrict__ bias, void* __restrict__ Cp, int N,
    int bm, int bn, ushort_t* As, ushort_t* Bs)
{
    const int tid  = threadIdx.x;
    const int wave = tid >> 6, lane = tid & 63;
    const int wm = (wave >> 1) * 64, wn = (wave & 1) * 64;
    const int c0 = 2 * wave, c1 = 2 * wave + 1;
    // staging: chunk c covers rows [c*16, c*16+16), lane l -> row c*16+(l>>2), k (l&3)*8
    const int kb = (lane & 3) * 8;
    const ushort_t* gA0 = A  + (size_t)(bm + c0 * 16 + (lane >> 2)) * 256 + kb;
    const ushort_t* gA1 = A  + (size_t)(bm + c1 * 16 + (lane >> 2)) * 256 + kb;
    const ushort_t* gB0 = BT + (size_t)(bn + c0 * 16 + (lane >> 2)) * 256 + kb;
    const ushort_t* gB1 = BT + (size_t)(bn + c1 * 16 + (lane >> 2)) * 256 + kb;
    ushort_t* lA0 = As + c0 * 512;   // 1024 B per chunk (wave-uniform base)
    ushort_t* lA1 = As + c1 * 512;
    ushort_t* lB0 = Bs + c0 * 512;
    ushort_t* lB1 = Bs + c1 * 512;

    f32x4 acc[4][4] = {};

    const int row = lane & 15, kg = (lane >> 4) * 8;
    for (int kt = 0; kt < 8; kt++) {
        gld16(gA0, lA0); gld16(gA1, lA1);
        gld16(gB0, lB0); gld16(gB1, lB1);
        gA0 += 32; gA1 += 32; gB0 += 32; gB1 += 32;
        __syncthreads();
        bf16x8 af[4], bfr[4];
#pragma unroll
        for (int i = 0; i < 4; i++)
            af[i] = *(const bf16x8*)(As + (wm + i * 16 + row) * 32 + kg);
#pragma unroll
        for (int j = 0; j < 4; j++)
            bfr[j] = *(const bf16x8*)(Bs + (wn + j * 16 + row) * 32 + kg);
#pragma unroll
        for (int i = 0; i < 4; i++)
#pragma unroll
            for (int j = 0; j < 4; j++)
                acc[i][j] = __builtin_amdgcn_mfma_f32_16x16x32_bf16(
                    af[i], bfr[j], acc[i][j], 0, 0, 0);
        __syncthreads();
    }

    // epilogue: C/D layout col=lane&15, row=(lane>>4)*4+reg
    const int col = lane & 15, rbase = (lane >> 4) * 4;
#pragma unroll
    for (int j = 0; j < 4; j++) {
        const int cc = bn + wn + j * 16 + col;
        const float bv = bias[cc];
#pragma unroll
        for (int i = 0; i < 4; i++) {
            const int rr = bm + wm + i * 16 + rbase;
#pragma unroll
            for (int r = 0; r < 4; r++) {
                const float v = acc[i][j][r] + bv;
                if (OUT_BF16) ((ushort_t*)Cp)[(size_t)(rr + r) * N + cc] = bfbits(v);
                else          ((float*)Cp)[(size_t)(rr + r) * N + cc] = v;
            }
        }
    }
}

// value GEMM (850 total blocks): [0,340) value = in_bf@WvT (bf16 out, N=256)
//                                [340,850) offattn = q_bf@WoaT (f32 out, N=384)
__global__ __launch_bounds__(256) void gemm_dual(
    const ushort_t* __restrict__ in_bf, const ushort_t* __restrict__ wvT,
    const float* __restrict__ b_val, ushort_t* __restrict__ value_bf,
    const ushort_t* __restrict__ q_bf, const ushort_t* __restrict__ woaT,
    const float* __restrict__ bias_oa, float* __restrict__ offattn)
{
    __shared__ ushort_t As[128 * 32];
    __shared__ ushort_t Bs[128 * 32];
    int blk = blockIdx.x;
    if (blk < 340) {
        const int bn = (blk & 1) * 128, bm = (blk >> 1) * 128;
        gemm_core<true>(in_bf, wvT, b_val, value_bf, 256, bm, bn, As, Bs);
    } else {
        blk -= 340;
        const int bn = (blk % 3) * 128, bm = (blk / 3) * 128;
        gemm_core<false>(q_bf, woaT, bias_oa, offattn, 384, bm, bn, As, Bs);
    }
}

__global__ __launch_bounds__(256) void gemm_out(
    const ushort_t* __restrict__ mid_bf, const ushort_t* __restrict__ woutT,
    const float* __restrict__ b_out, float* __restrict__ out)
{
    __shared__ ushort_t As[128 * 32];
    __shared__ ushort_t Bs[128 * 32];
    const int bn = (blockIdx.x & 1) * 128, bm = (blockIdx.x >> 1) * 128;
    gemm_core<false>(mid_bf, woutT, b_out, out, 256, bm, bn, As, Bs);
}

// ======================= softmax + bilinear sampling (bf16 value) =======================
// 256 threads = 8 queries x (8 heads x 4 lanes); lane owns 8 bf16 channels (16 B).
__device__ __forceinline__ void acc8(float* acc, uint4 v, float w) {
    const unsigned* p = &v.x;
#pragma unroll
    for (int d = 0; d < 4; d++) {
        const unsigned u = p[d];
        const float lo = __uint_as_float(u << 16);
        const float hi = __uint_as_float(u & 0xFFFF0000u);
        acc[2 * d]     = fmaf(w, lo, acc[2 * d]);
        acc[2 * d + 1] = fmaf(w, hi, acc[2 * d + 1]);
    }
}

__global__ __launch_bounds__(256) void msda_sample_bf16(
    const ushort_t* __restrict__ value, const float* __restrict__ refp,
    const float* __restrict__ offattn, ushort_t* __restrict__ mid)
{
    constexpr int LVL_H[4]  = {64, 32, 16, 8};
    constexpr int LVL_W[4]  = {64, 32, 16, 8};
    constexpr int LVL_ST[4] = {0, 4096, 5120, 5376};

    const int tid  = threadIdx.x;
    const int bq   = blockIdx.x * 8 + (tid >> 5);
    const int b    = bq / LEN_Q;
    const int t32  = tid & 31;
    const int head = t32 >> 2;
    const int c8   = (t32 & 3) * 8;

    const float* base = offattn + (size_t)bq * 384;
    // logits for this head
    const float* lp = base + 256 + head * 16;
    float4 l0 = ((const float4*)lp)[0];
    float4 l1 = ((const float4*)lp)[1];
    float4 l2 = ((const float4*)lp)[2];
    float4 l3 = ((const float4*)lp)[3];
    float lg[16] = {l0.x, l0.y, l0.z, l0.w, l1.x, l1.y, l1.z, l1.w,
                    l2.x, l2.y, l2.z, l2.w, l3.x, l3.y, l3.z, l3.w};
    float mx = lg[0];
#pragma unroll
    for (int j = 1; j < 16; j++) mx = fmaxf(mx, lg[j]);

    // offsets for this head
    const float* op = base + head * 32;
    float4 ov[8];
#pragma unroll
    for (int j = 0; j < 8; j++) ov[j] = ((const float4*)op)[j];
    const float* rp = refp + (size_t)bq * 8;
    float4 r0 = ((const float4*)rp)[0];
    float4 r1 = ((const float4*)rp)[1];
    const float rx[4] = {r0.x, r0.z, r1.x, r1.z};
    const float ry[4] = {r0.y, r0.w, r1.y, r1.w};

    const ushort_t* vbase = value + (size_t)b * LEN_IN * 256 + head * 32 + c8;

    float acc[8] = {};
    float esum = 0.f;

#pragma unroll
    for (int l = 0; l < 4; l++) {
        const int H = LVL_H[l], W = LVL_W[l], st = LVL_ST[l];
        const float fW = (float)W, fH = (float)H;
#pragma unroll
        for (int p = 0; p < 4; p++) {
            const float* o2 = &ov[l * 2].x;
            const float ox = o2[p * 2 + 0];
            const float oy = o2[p * 2 + 1];
            const float x = (rx[l] + ox / fW) * fW - 0.5f;
            const float y = (ry[l] + oy / fH) * fH - 0.5f;
            const float x0f = floorf(x), y0f = floorf(y);
            const float wx = x - x0f, wy = y - y0f;
            const int ix0 = (int)x0f, iy0 = (int)y0f;
            const int ix1 = ix0 + 1,  iy1 = iy0 + 1;
            const float vx0 = (ix0 >= 0 && ix0 < W) ? 1.f : 0.f;
            const float vx1 = (ix1 >= 0 && ix1 < W) ? 1.f : 0.f;
            const float vy0 = (iy0 >= 0 && iy0 < H) ? 1.f : 0.f;
            const float vy1 = (iy1 >= 0 && iy1 < H) ? 1.f : 0.f;
            const int cx0 = min(max(ix0, 0), W - 1);
            const int cx1 = min(max(ix1, 0), W - 1);
            const int cy0 = min(max(iy0, 0), H - 1);
            const int cy1 = min(max(iy1, 0), H - 1);
            const float hx0 = (1.f - wx) * vx0, hx1 = wx * vx1;
            const float hy0 = (1.f - wy) * vy0, hy1 = wy * vy1;

            const ushort_t* rp0 = vbase + (size_t)(st + cy0 * W) * 256;
            const ushort_t* rp1 = vbase + (size_t)(st + cy1 * W) * 256;
            uint4 v00 = *(const uint4*)(rp0 + (size_t)cx0 * 256);
            uint4 v01 = *(const uint4*)(rp0 + (size_t)cx1 * 256);
            uint4 v10 = *(const uint4*)(rp1 + (size_t)cx0 * 256);
            uint4 v11 = *(const uint4*)(rp1 + (size_t)cx1 * 256);

            const float e = __expf(lg[l * 4 + p] - mx);
            esum += e;
            acc8(acc, v00, e * hx0 * hy0);
            acc8(acc, v01, e * hx1 * hy0);
            acc8(acc, v10, e * hx0 * hy1);
            acc8(acc, v11, e * hx1 * hy1);
        }
    }

    const float inv = 1.f / esum;
    uint4 o;
    o.x = pk2(acc[0] * inv, acc[1] * inv);
    o.y = pk2(acc[2] * inv, acc[3] * inv);
    o.z = pk2(acc[4] * inv, acc[5] * inv);
    o.w = pk2(acc[6] * inv, acc[7] * inv);
    *(uint4*)(mid + (size_t)bq * 256 + head * 32 + c8) = o;
}

// ======================= launch =======================
extern "C" void kernel_launch(void* const* d_in, const int* in_sizes, int n_in,
                              void* d_out, int out_size, void* d_ws, size_t ws_size,
                              hipStream_t stream)
{
    const float* query  = (const float*)d_in[0];
    const float* refp   = (const float*)d_in[1];
    const float* inflat = (const float*)d_in[2];
    const float* W_val  = (const float*)d_in[5];
    const float* b_val  = (const float*)d_in[6];
    const float* W_off  = (const float*)d_in[7];
    const float* W_attn = (const float*)d_in[9];
    const float* b_off  = (const float*)d_in[8];
    const float* b_attn = (const float*)d_in[10];
    const float* W_out  = (const float*)d_in[11];
    const float* b_out  = (const float*)d_in[12];
    float* out = (float*)d_out;

    // workspace layout (bytes)
    char* ws = (char*)d_ws;
    ushort_t* in_bf    = (ushort_t*)ws;                               // 11,141,120 (reused as mid_bf)
    ushort_t* q_bf     = (ushort_t*)(ws + 11141120);                  // 11,141,120
    ushort_t* value_bf = (ushort_t*)(ws + 22282240);                  // 11,141,120
    ushort_t* wvT      = (ushort_t*)(ws + 33423360);                  // 131,072
    ushort_t* woutT    = (ushort_t*)(ws + 33554432);                  // 131,072
    ushort_t* woaT     = (ushort_t*)(ws + 33685504);                  // 196,608
    float*    bias_oa  = (float*)   (ws + 33882112);                  // 1,536
    float*    offattn  = (float*)   (ws + 33883648);                  // 33,423,360
    ushort_t* mid_bf   = in_bf;   // overlay: in_bf dead after gemm_dual

    dim3 blk(256);
    pack_inputs<<<dim3(5553), blk, 0, stream>>>(
        inflat, query, W_val, W_off, W_attn, W_out, b_off, b_attn,
        in_bf, q_bf, wvT, woaT, woutT, bias_oa);
    gemm_dual<<<dim3(850), blk, 0, stream>>>(
        in_bf, wvT, b_val, value_bf, q_bf, woaT, bias_oa, offattn);
    msda_sample_bf16<<<dim3(M_TOT / 8), blk, 0, stream>>>(
        value_bf, refp, offattn, mid_bf);
    gemm_out<<<dim3(340), blk, 0, stream>>>(
        mid_bf, woutT, b_out, out);
}